// Round 1
// baseline (323.468 us; speedup 1.0000x reference)
//
#include <hip/hip_runtime.h>

#define N_FUNC 10000
#define N_IN   2000
#define N_OUT  2000
#define CCH    8
#define K_FF   16
#define E_TOTAL 170000
#define E_FF    160000   // ff edges: dst[e] = e/16 (structural)
#define E_W1    168000   // ff+if edges (dst < N_FUNC)
#define E_IF    8000
#define HDIM    80000
#define BATCH   64
#define N_LAYERS 4
#define EPS_LN  1e-5f

// ---------------- CSR build helpers (run once per call) ----------------

__global__ void zero2(int* __restrict__ a, int* __restrict__ b, int n) {
    int i = blockIdx.x * blockDim.x + threadIdx.x;
    if (i < n) { a[i] = 0; b[i] = 0; }
}

__global__ void count_edges(const int* __restrict__ src, const int* __restrict__ dst,
                            int* __restrict__ if_cnt, int* __restrict__ src_cnt) {
    int i = blockIdx.x * blockDim.x + threadIdx.x;
    if (i < E_IF) {
        atomicAdd(&if_cnt[dst[E_FF + i]], 1);
    }
    if (i < E_FF + N_OUT) {
        int e = (i < E_FF) ? i : (E_W1 + (i - E_FF));
        atomicAdd(&src_cnt[src[e]], 1);
    }
}

// single-block exclusive scan over N_FUNC counts; block 0 -> if, block 1 -> src
__global__ __launch_bounds__(1024) void scan2(
        const int* __restrict__ if_cnt, int* __restrict__ if_off, int* __restrict__ if_cur,
        const int* __restrict__ src_cnt, int* __restrict__ src_off, int* __restrict__ src_cur) {
    const int n = N_FUNC;
    const int* cnt; int* off; int* cur;
    if (blockIdx.x == 0) { cnt = if_cnt;  off = if_off;  cur = if_cur;  }
    else                 { cnt = src_cnt; off = src_off; cur = src_cur; }
    __shared__ int buf[1024];
    int t = threadIdx.x;
    const int per = (n + 1023) >> 10;   // 10
    int base = t * per;
    int local[10];
    int s = 0;
    for (int i = 0; i < per; i++) {
        int idx = base + i;
        int v = (idx < n) ? cnt[idx] : 0;
        local[i] = s;
        s += v;
    }
    buf[t] = s;
    __syncthreads();
    for (int o = 1; o < 1024; o <<= 1) {
        int add = (t >= o) ? buf[t - o] : 0;
        __syncthreads();
        buf[t] += add;
        __syncthreads();
    }
    int excl = buf[t] - s;
    for (int i = 0; i < per; i++) {
        int idx = base + i;
        if (idx < n) { int v = excl + local[i]; off[idx] = v; cur[idx] = v; }
    }
    if (t == 1023) off[n] = buf[1023];
}

__global__ void fill_edges(const int* __restrict__ src, const int* __restrict__ dst,
                           int* __restrict__ if_cur, int* __restrict__ if_edges,
                           int* __restrict__ src_cur, int* __restrict__ src_edges) {
    int i = blockIdx.x * blockDim.x + threadIdx.x;
    if (i < E_IF) {
        int e = E_FF + i;
        int pos = atomicAdd(&if_cur[dst[e]], 1);
        if_edges[pos] = e;
    }
    if (i < E_FF + N_OUT) {
        int e = (i < E_FF) ? i : (E_W1 + (i - E_FF));
        int pos = atomicAdd(&src_cur[src[e]], 1);
        src_edges[pos] = e;
    }
}

// ---------------- xe init: xe[e][b] layout, [E][64] ----------------
// xe = x_node[:, src]: zero except if-edges, where e = 160000 + i*4 + k -> x[b][i]

__global__ void init_xe(const float* __restrict__ x, float* __restrict__ xe) {
    int i = blockIdx.x * blockDim.x + threadIdx.x;   // E_TOTAL*64 threads
    if (i >= E_TOTAL * BATCH) return;
    int e = i >> 6;
    int lane = i & 63;
    float v = 0.0f;
    if (e >= E_FF && e < E_W1) {
        int ii = (e - E_FF) >> 2;
        v = x[lane * N_IN + ii];
    }
    xe[i] = v;
}

// ---------------- layer phase A+B: gather -> group-LN -> GELU ----------------
// one wave per function node; lane = batch index

__global__ __launch_bounds__(256) void layer_k1(
        const float* __restrict__ xe, const float* __restrict__ w1,
        const float* __restrict__ b1, const float* __restrict__ gamma,
        const float* __restrict__ beta, const int* __restrict__ if_off,
        const int* __restrict__ if_edges, float* __restrict__ h) {
    int wid = (blockIdx.x * blockDim.x + threadIdx.x) >> 6;
    int lane = threadIdx.x & 63;
    int f = __builtin_amdgcn_readfirstlane(wid);
    if (f >= N_FUNC) return;

    float acc[CCH];
    #pragma unroll
    for (int c = 0; c < CCH; c++) acc[c] = b1[f * CCH + c];

    // ff edges: e = 16f..16f+15 (structural CSR)
    #pragma unroll 2
    for (int k = 0; k < K_FF; k++) {
        int e = f * K_FF + k;
        float xv = xe[e * BATCH + lane];
        #pragma unroll
        for (int c = 0; c < CCH; c++) acc[c] += xv * w1[e * CCH + c];
    }
    // scattered if-edges via runtime CSR
    int j0 = if_off[f], j1 = if_off[f + 1];
    for (int j = j0; j < j1; j++) {
        int e = if_edges[j];
        float xv = xe[e * BATCH + lane];
        #pragma unroll
        for (int c = 0; c < CCH; c++) acc[c] += xv * w1[e * CCH + c];
    }

    // group-LN over the 8 channels (lane-local!) + exact GELU
    float mu = 0.f;
    #pragma unroll
    for (int c = 0; c < CCH; c++) mu += acc[c];
    mu *= 0.125f;
    float var = 0.f;
    #pragma unroll
    for (int c = 0; c < CCH; c++) { float d = acc[c] - mu; var += d * d; }
    var *= 0.125f;
    float rs = rsqrtf(var + EPS_LN);
    #pragma unroll
    for (int c = 0; c < CCH; c++) {
        float g = (acc[c] - mu) * rs * gamma[f * CCH + c] + beta[f * CCH + c];
        float ge = 0.5f * g * (1.0f + erff(g * 0.70710678118654752f));
        h[(f * CCH + c) * BATCH + lane] = ge;
    }
}

// ---------------- layer phase C: per-src-node scatter + residual ----------------
// waves [0, N_FUNC): function src nodes; waves [N_FUNC, N_FUNC+E_IF): if-edge bias-only

__global__ __launch_bounds__(256) void layer_k2(
        float* __restrict__ xe, const float* __restrict__ h,
        const float* __restrict__ w3, const float* __restrict__ b3,
        const int* __restrict__ src_off, const int* __restrict__ src_edges) {
    int wid = (blockIdx.x * blockDim.x + threadIdx.x) >> 6;
    int lane = threadIdx.x & 63;
    int s = __builtin_amdgcn_readfirstlane(wid);
    if (s < N_FUNC) {
        float hreg[CCH];
        #pragma unroll
        for (int c = 0; c < CCH; c++) hreg[c] = h[(s * CCH + c) * BATCH + lane];
        int j0 = src_off[s], j1 = src_off[s + 1];
        for (int j = j0; j < j1; j++) {
            int e = src_edges[j];
            int p = (e < E_FF) ? e : (e - E_IF);   // w3 COO row index
            float acc = xe[e * BATCH + lane] + b3[e];
            #pragma unroll
            for (int c = 0; c < CCH; c++) acc += hreg[c] * w3[p * CCH + c];
            xe[e * BATCH + lane] = acc;
        }
    } else {
        int e = E_FF + (s - N_FUNC);   // if-edge: residual + bias only
        if (e < E_W1) xe[e * BATCH + lane] += b3[e];
    }
}

// ---------------- output: transpose the last 2000 edge rows, /LAYERS ----------------

__global__ void write_out(const float* __restrict__ xe, float* __restrict__ out) {
    int i = blockIdx.x * blockDim.x + threadIdx.x;   // N_OUT*64
    if (i >= N_OUT * BATCH) return;
    int j = i >> 6;
    int lane = i & 63;
    out[lane * N_OUT + j] = xe[(E_W1 + j) * BATCH + lane] * (1.0f / N_LAYERS);
}

// ---------------- launch ----------------

extern "C" void kernel_launch(void* const* d_in, const int* in_sizes, int n_in,
                              void* d_out, int out_size, void* d_ws, size_t ws_size,
                              hipStream_t stream) {
    const float* x      = (const float*)d_in[0];
    const float* w1_val = (const float*)d_in[1];
    const float* b1     = (const float*)d_in[2];
    const float* w3_val = (const float*)d_in[3];
    const float* b3     = (const float*)d_in[4];
    const float* gamma  = (const float*)d_in[5];
    const float* beta   = (const float*)d_in[6];
    const int* edge_src = (const int*)d_in[7];
    const int* edge_dst = (const int*)d_in[8];
    float* out = (float*)d_out;

    char* base = (char*)d_ws;
    size_t off = 0;
    auto alloc = [&](size_t bytes) -> void* {
        void* p = base + off;
        off += (bytes + 255) & ~(size_t)255;
        return p;
    };
    float* xe      = (float*)alloc((size_t)E_TOTAL * BATCH * 4);
    float* h       = (float*)alloc((size_t)HDIM * BATCH * 4);
    int* if_cnt    = (int*)alloc(N_FUNC * 4);
    int* src_cnt   = (int*)alloc(N_FUNC * 4);
    int* if_offs   = (int*)alloc((N_FUNC + 1) * 4);
    int* src_offs  = (int*)alloc((N_FUNC + 1) * 4);
    int* if_cur    = (int*)alloc(N_FUNC * 4);
    int* src_cur   = (int*)alloc(N_FUNC * 4);
    int* if_edges  = (int*)alloc(E_IF * 4);
    int* src_edges = (int*)alloc((E_FF + N_OUT) * 4);
    (void)ws_size; (void)in_sizes; (void)n_in; (void)out_size;

    // CSR build (ws is re-poisoned every call, so rebuild every call)
    zero2<<<(N_FUNC + 255) / 256, 256, 0, stream>>>(if_cnt, src_cnt, N_FUNC);
    count_edges<<<(E_FF + N_OUT + 255) / 256, 256, 0, stream>>>(edge_src, edge_dst, if_cnt, src_cnt);
    scan2<<<2, 1024, 0, stream>>>(if_cnt, if_offs, if_cur, src_cnt, src_offs, src_cur);
    fill_edges<<<(E_FF + N_OUT + 255) / 256, 256, 0, stream>>>(edge_src, edge_dst,
                                                              if_cur, if_edges, src_cur, src_edges);

    init_xe<<<(E_TOTAL * BATCH) / 256, 256, 0, stream>>>(x, xe);

    for (int l = 0; l < N_LAYERS; l++) {
        layer_k1<<<(N_FUNC * BATCH) / 256, 256, 0, stream>>>(
            xe, w1_val, b1, gamma, beta, if_offs, if_edges, h);
        layer_k2<<<((N_FUNC + E_IF) * BATCH) / 256, 256, 0, stream>>>(
            xe, h, w3_val, b3, src_offs, src_edges);
    }

    write_out<<<(N_OUT * BATCH) / 256, 256, 0, stream>>>(xe, out);
}

// Round 2
// 265.594 us; speedup vs baseline: 1.2179x; 1.2179x over previous
//
#include <hip/hip_runtime.h>

#define N_FUNC 10000
#define N_IN   2000
#define N_OUT  2000
#define CCH    8
#define K_FF   16
#define E_TOTAL 170000
#define E_FF    160000   // ff edges: dst[e] = e/16 (structural)
#define E_W1    168000   // ff+if edges (dst < N_FUNC)
#define E_IF    8000
#define HDIM    80000
#define BATCH   64
#define N_LAYERS 4
#define EPS_LN  1e-5f

// ---------------- CSR build helpers (run once per call) ----------------

__global__ void zero2(int* __restrict__ a, int* __restrict__ b, int n) {
    int i = blockIdx.x * blockDim.x + threadIdx.x;
    if (i < n) { a[i] = 0; b[i] = 0; }
}

__global__ void count_edges(const int* __restrict__ src, const int* __restrict__ dst,
                            int* __restrict__ if_cnt, int* __restrict__ src_cnt) {
    int i = blockIdx.x * blockDim.x + threadIdx.x;
    if (i < E_IF) {
        atomicAdd(&if_cnt[dst[E_FF + i]], 1);
    }
    if (i < E_FF + N_OUT) {
        int e = (i < E_FF) ? i : (E_W1 + (i - E_FF));
        atomicAdd(&src_cnt[src[e]], 1);
    }
}

// single-block exclusive scan over N_FUNC counts; block 0 -> if, block 1 -> src
__global__ __launch_bounds__(1024) void scan2(
        const int* __restrict__ if_cnt, int* __restrict__ if_off, int* __restrict__ if_cur,
        const int* __restrict__ src_cnt, int* __restrict__ src_off, int* __restrict__ src_cur) {
    const int n = N_FUNC;
    const int* cnt; int* off; int* cur;
    if (blockIdx.x == 0) { cnt = if_cnt;  off = if_off;  cur = if_cur;  }
    else                 { cnt = src_cnt; off = src_off; cur = src_cur; }
    __shared__ int buf[1024];
    int t = threadIdx.x;
    const int per = (n + 1023) >> 10;   // 10
    int base = t * per;
    int local[10];
    int s = 0;
    for (int i = 0; i < per; i++) {
        int idx = base + i;
        int v = (idx < n) ? cnt[idx] : 0;
        local[i] = s;
        s += v;
    }
    buf[t] = s;
    __syncthreads();
    for (int o = 1; o < 1024; o <<= 1) {
        int add = (t >= o) ? buf[t - o] : 0;
        __syncthreads();
        buf[t] += add;
        __syncthreads();
    }
    int excl = buf[t] - s;
    for (int i = 0; i < per; i++) {
        int idx = base + i;
        if (idx < n) { int v = excl + local[i]; off[idx] = v; cur[idx] = v; }
    }
    if (t == 1023) off[n] = buf[1023];
}

__global__ void fill_edges(const int* __restrict__ src, const int* __restrict__ dst,
                           int* __restrict__ if_cur, int* __restrict__ if_edges,
                           int* __restrict__ src_cur, int* __restrict__ src_edges) {
    int i = blockIdx.x * blockDim.x + threadIdx.x;
    if (i < E_IF) {
        int e = E_FF + i;
        int pos = atomicAdd(&if_cur[dst[e]], 1);
        if_edges[pos] = e;
    }
    if (i < E_FF + N_OUT) {
        int e = (i < E_FF) ? i : (E_W1 + (i - E_FF));
        int pos = atomicAdd(&src_cur[src[e]], 1);
        src_edges[pos] = e;
    }
}

// ---------------- x transpose: xT[i][b] = x[b][i] (512 KB, L2-resident) -------

__global__ void transpose_x(const float* __restrict__ x, float* __restrict__ xT) {
    int wid = (blockIdx.x * blockDim.x + threadIdx.x) >> 6;   // input column i
    int lane = threadIdx.x & 63;                              // batch
    if (wid >= N_IN) return;
    xT[wid * BATCH + lane] = x[lane * N_IN + wid];
}

// ---------------- layer phase A+B: gather -> group-LN -> GELU ----------------
// one wave per function node; lane = batch index.
// if-edge xe rows are virtual: value at layer l is xT[i] + l*b3[e].

__global__ __launch_bounds__(256) void layer_k1(
        const float* __restrict__ xe, const float* __restrict__ xT,
        const float* __restrict__ w1, const float* __restrict__ b1,
        const float* __restrict__ gamma, const float* __restrict__ beta,
        const float* __restrict__ b3, const int* __restrict__ if_off,
        const int* __restrict__ if_edges, float* __restrict__ h, int layer) {
    int wid = (blockIdx.x * blockDim.x + threadIdx.x) >> 6;
    int lane = threadIdx.x & 63;
    int f = __builtin_amdgcn_readfirstlane(wid);
    if (f >= N_FUNC) return;

    float acc[CCH];
    #pragma unroll
    for (int c = 0; c < CCH; c++) acc[c] = b1[f * CCH + c];

    if (layer > 0) {
        // ff edges: e = 16f..16f+15 (structural CSR); all 16 loads in flight
        float xv[K_FF];
        #pragma unroll
        for (int k = 0; k < K_FF; k++) xv[k] = xe[(f * K_FF + k) * BATCH + lane];
        #pragma unroll
        for (int k = 0; k < K_FF; k++) {
            int e = f * K_FF + k;
            #pragma unroll
            for (int c = 0; c < CCH; c++) acc[c] += xv[k] * w1[e * CCH + c];
        }
    }
    // scattered if-edges via runtime CSR; xe row virtual = xT + layer*b3
    int j0 = if_off[f], j1 = if_off[f + 1];
    float lf = (float)layer;
    for (int j = j0; j < j1; j++) {
        int e = if_edges[j];
        int ii = (e - E_FF) >> 2;
        float xv = xT[ii * BATCH + lane] + lf * b3[e];
        #pragma unroll
        for (int c = 0; c < CCH; c++) acc[c] += xv * w1[e * CCH + c];
    }

    // group-LN over the 8 channels (lane-local!) + exact GELU
    float mu = 0.f;
    #pragma unroll
    for (int c = 0; c < CCH; c++) mu += acc[c];
    mu *= 0.125f;
    float var = 0.f;
    #pragma unroll
    for (int c = 0; c < CCH; c++) { float d = acc[c] - mu; var += d * d; }
    var *= 0.125f;
    float rs = rsqrtf(var + EPS_LN);
    #pragma unroll
    for (int c = 0; c < CCH; c++) {
        float g = (acc[c] - mu) * rs * gamma[f * CCH + c] + beta[f * CCH + c];
        float ge = 0.5f * g * (1.0f + erff(g * 0.70710678118654752f));
        h[(f * CCH + c) * BATCH + lane] = ge;
    }
}

// ---------------- layer phase C: per-src-node scatter + residual ----------------
// FIRST layer: xe rows are all zero -> pure store, no read.

template <bool FIRST>
__device__ __forceinline__ void k2_body(
        float* __restrict__ xe, const float* __restrict__ h,
        const float* __restrict__ w3, const float* __restrict__ b3,
        const int* __restrict__ src_off, const int* __restrict__ src_edges,
        int s, int lane) {
    float hreg[CCH];
    #pragma unroll
    for (int c = 0; c < CCH; c++) hreg[c] = h[(s * CCH + c) * BATCH + lane];
    int j0 = src_off[s], j1 = src_off[s + 1];
    int j = j0;
    for (; j + 4 <= j1; j += 4) {
        int e0 = src_edges[j], e1 = src_edges[j + 1];
        int e2 = src_edges[j + 2], e3 = src_edges[j + 3];
        float r0 = 0.f, r1 = 0.f, r2 = 0.f, r3 = 0.f;
        if (!FIRST) {
            r0 = xe[e0 * BATCH + lane];
            r1 = xe[e1 * BATCH + lane];
            r2 = xe[e2 * BATCH + lane];
            r3 = xe[e3 * BATCH + lane];
        }
        int p0 = (e0 < E_FF) ? e0 : (e0 - E_IF);
        int p1 = (e1 < E_FF) ? e1 : (e1 - E_IF);
        int p2 = (e2 < E_FF) ? e2 : (e2 - E_IF);
        int p3 = (e3 < E_FF) ? e3 : (e3 - E_IF);
        float a0 = b3[e0], a1 = b3[e1], a2 = b3[e2], a3 = b3[e3];
        #pragma unroll
        for (int c = 0; c < CCH; c++) {
            a0 += hreg[c] * w3[p0 * CCH + c];
            a1 += hreg[c] * w3[p1 * CCH + c];
            a2 += hreg[c] * w3[p2 * CCH + c];
            a3 += hreg[c] * w3[p3 * CCH + c];
        }
        xe[e0 * BATCH + lane] = a0 + r0;
        xe[e1 * BATCH + lane] = a1 + r1;
        xe[e2 * BATCH + lane] = a2 + r2;
        xe[e3 * BATCH + lane] = a3 + r3;
    }
    for (; j < j1; j++) {
        int e = src_edges[j];
        int p = (e < E_FF) ? e : (e - E_IF);
        float a = b3[e];
        if (!FIRST) a += xe[e * BATCH + lane];
        #pragma unroll
        for (int c = 0; c < CCH; c++) a += hreg[c] * w3[p * CCH + c];
        xe[e * BATCH + lane] = a;
    }
}

__global__ __launch_bounds__(256) void layer_k2_first(
        float* __restrict__ xe, const float* __restrict__ h,
        const float* __restrict__ w3, const float* __restrict__ b3,
        const int* __restrict__ src_off, const int* __restrict__ src_edges) {
    int wid = (blockIdx.x * blockDim.x + threadIdx.x) >> 6;
    int lane = threadIdx.x & 63;
    int s = __builtin_amdgcn_readfirstlane(wid);
    if (s < N_FUNC) k2_body<true>(xe, h, w3, b3, src_off, src_edges, s, lane);
}

__global__ __launch_bounds__(256) void layer_k2_mid(
        float* __restrict__ xe, const float* __restrict__ h,
        const float* __restrict__ w3, const float* __restrict__ b3,
        const int* __restrict__ src_off, const int* __restrict__ src_edges) {
    int wid = (blockIdx.x * blockDim.x + threadIdx.x) >> 6;
    int lane = threadIdx.x & 63;
    int s = __builtin_amdgcn_readfirstlane(wid);
    if (s < N_FUNC) k2_body<false>(xe, h, w3, b3, src_off, src_edges, s, lane);
}

// ---------------- last layer: only the 2000 fo edges matter -> fused output ----

__global__ __launch_bounds__(256) void layer_k2_last(
        const float* __restrict__ xe, const float* __restrict__ h,
        const float* __restrict__ w3, const float* __restrict__ b3,
        const int* __restrict__ edge_src, float* __restrict__ out) {
    int wid = (blockIdx.x * blockDim.x + threadIdx.x) >> 6;   // fo index j
    int lane = threadIdx.x & 63;
    int j = __builtin_amdgcn_readfirstlane(wid);
    if (j >= N_OUT) return;
    int e = E_W1 + j;
    int s = edge_src[e];           // uniform -> s_load
    int p = e - E_IF;
    float acc = xe[e * BATCH + lane] + b3[e];
    float hreg[CCH];
    #pragma unroll
    for (int c = 0; c < CCH; c++) hreg[c] = h[(s * CCH + c) * BATCH + lane];
    #pragma unroll
    for (int c = 0; c < CCH; c++) acc += hreg[c] * w3[p * CCH + c];
    out[lane * N_OUT + j] = acc * (1.0f / N_LAYERS);
}

// ---------------- launch ----------------

extern "C" void kernel_launch(void* const* d_in, const int* in_sizes, int n_in,
                              void* d_out, int out_size, void* d_ws, size_t ws_size,
                              hipStream_t stream) {
    const float* x      = (const float*)d_in[0];
    const float* w1_val = (const float*)d_in[1];
    const float* b1     = (const float*)d_in[2];
    const float* w3_val = (const float*)d_in[3];
    const float* b3     = (const float*)d_in[4];
    const float* gamma  = (const float*)d_in[5];
    const float* beta   = (const float*)d_in[6];
    const int* edge_src = (const int*)d_in[7];
    const int* edge_dst = (const int*)d_in[8];
    float* out = (float*)d_out;

    char* base = (char*)d_ws;
    size_t off = 0;
    auto alloc = [&](size_t bytes) -> void* {
        void* p = base + off;
        off += (bytes + 255) & ~(size_t)255;
        return p;
    };
    float* xe      = (float*)alloc((size_t)E_TOTAL * BATCH * 4);  // if rows unused
    float* h       = (float*)alloc((size_t)HDIM * BATCH * 4);
    float* xT      = (float*)alloc((size_t)N_IN * BATCH * 4);
    int* if_cnt    = (int*)alloc(N_FUNC * 4);
    int* src_cnt   = (int*)alloc(N_FUNC * 4);
    int* if_offs   = (int*)alloc((N_FUNC + 1) * 4);
    int* src_offs  = (int*)alloc((N_FUNC + 1) * 4);
    int* if_cur    = (int*)alloc(N_FUNC * 4);
    int* src_cur   = (int*)alloc(N_FUNC * 4);
    int* if_edges  = (int*)alloc(E_IF * 4);
    int* src_edges = (int*)alloc((E_FF + N_OUT) * 4);
    (void)ws_size; (void)in_sizes; (void)n_in; (void)out_size;

    // CSR build (ws is re-poisoned every call, so rebuild every call)
    zero2<<<(N_FUNC + 255) / 256, 256, 0, stream>>>(if_cnt, src_cnt, N_FUNC);
    count_edges<<<(E_FF + N_OUT + 255) / 256, 256, 0, stream>>>(edge_src, edge_dst, if_cnt, src_cnt);
    scan2<<<2, 1024, 0, stream>>>(if_cnt, if_offs, if_cur, src_cnt, src_offs, src_cur);
    fill_edges<<<(E_FF + N_OUT + 255) / 256, 256, 0, stream>>>(edge_src, edge_dst,
                                                              if_cur, if_edges, src_cur, src_edges);
    transpose_x<<<(N_IN * BATCH) / 256, 256, 0, stream>>>(x, xT);

    for (int l = 0; l < N_LAYERS; l++) {
        layer_k1<<<(N_FUNC * BATCH) / 256, 256, 0, stream>>>(
            xe, xT, w1_val, b1, gamma, beta, b3, if_offs, if_edges, h, l);
        if (l == 0) {
            layer_k2_first<<<(N_FUNC * BATCH) / 256, 256, 0, stream>>>(
                xe, h, w3_val, b3, src_offs, src_edges);
        } else if (l < N_LAYERS - 1) {
            layer_k2_mid<<<(N_FUNC * BATCH) / 256, 256, 0, stream>>>(
                xe, h, w3_val, b3, src_offs, src_edges);
        } else {
            layer_k2_last<<<(N_OUT * BATCH) / 256, 256, 0, stream>>>(
                xe, h, w3_val, b3, edge_src, out);
        }
    }
}

// Round 3
// 240.943 us; speedup vs baseline: 1.3425x; 1.1023x over previous
//
#include <hip/hip_runtime.h>

#define N_FUNC 10000
#define N_IN   2000
#define N_OUT  2000
#define CCH    8
#define K_FF   16
#define E_TOTAL 170000
#define E_FF    160000   // ff edges: dst[e] = e/16 (structural)
#define E_W1    168000   // ff+if edges (dst < N_FUNC)
#define E_IF    8000
#define HDIM    80000
#define BATCH   64
#define N_LAYERS 4
#define EPS_LN  1e-5f

// bf16 storage helpers: fp32 math everywhere, RNE on store.
__device__ __forceinline__ float bf2f(unsigned short u) {
    unsigned int x = ((unsigned int)u) << 16;
    return __builtin_bit_cast(float, x);
}
__device__ __forceinline__ unsigned short f2bf(float f) {
    unsigned int x = __builtin_bit_cast(unsigned int, f);
    unsigned int r = x + 0x7FFFu + ((x >> 16) & 1u);
    return (unsigned short)(r >> 16);
}

// ---------------- CSR build helpers (run once per call) ----------------

__global__ void zero2(int* __restrict__ a, int* __restrict__ b, int n) {
    int i = blockIdx.x * blockDim.x + threadIdx.x;
    if (i < n) { a[i] = 0; b[i] = 0; }
}

__global__ void count_edges(const int* __restrict__ src, const int* __restrict__ dst,
                            int* __restrict__ if_cnt, int* __restrict__ src_cnt) {
    int i = blockIdx.x * blockDim.x + threadIdx.x;
    if (i < E_IF) {
        atomicAdd(&if_cnt[dst[E_FF + i]], 1);
    }
    if (i < E_FF + N_OUT) {
        int e = (i < E_FF) ? i : (E_W1 + (i - E_FF));
        atomicAdd(&src_cnt[src[e]], 1);
    }
}

// single-block exclusive scan over N_FUNC counts; block 0 -> if, block 1 -> src
__global__ __launch_bounds__(1024) void scan2(
        const int* __restrict__ if_cnt, int* __restrict__ if_off, int* __restrict__ if_cur,
        const int* __restrict__ src_cnt, int* __restrict__ src_off, int* __restrict__ src_cur) {
    const int n = N_FUNC;
    const int* cnt; int* off; int* cur;
    if (blockIdx.x == 0) { cnt = if_cnt;  off = if_off;  cur = if_cur;  }
    else                 { cnt = src_cnt; off = src_off; cur = src_cur; }
    __shared__ int buf[1024];
    int t = threadIdx.x;
    const int per = (n + 1023) >> 10;   // 10
    int base = t * per;
    int local[10];
    int s = 0;
    for (int i = 0; i < per; i++) {
        int idx = base + i;
        int v = (idx < n) ? cnt[idx] : 0;
        local[i] = s;
        s += v;
    }
    buf[t] = s;
    __syncthreads();
    for (int o = 1; o < 1024; o <<= 1) {
        int add = (t >= o) ? buf[t - o] : 0;
        __syncthreads();
        buf[t] += add;
        __syncthreads();
    }
    int excl = buf[t] - s;
    for (int i = 0; i < per; i++) {
        int idx = base + i;
        if (idx < n) { int v = excl + local[i]; off[idx] = v; cur[idx] = v; }
    }
    if (t == 1023) off[n] = buf[1023];
}

__global__ void fill_edges(const int* __restrict__ src, const int* __restrict__ dst,
                           int* __restrict__ if_cur, int* __restrict__ if_edges,
                           int* __restrict__ src_cur, int* __restrict__ src_edges) {
    int i = blockIdx.x * blockDim.x + threadIdx.x;
    if (i < E_IF) {
        int e = E_FF + i;
        int pos = atomicAdd(&if_cur[dst[e]], 1);
        if_edges[pos] = e;
    }
    if (i < E_FF + N_OUT) {
        int e = (i < E_FF) ? i : (E_W1 + (i - E_FF));
        int pos = atomicAdd(&src_cur[src[e]], 1);
        src_edges[pos] = e;
    }
}

// ---------------- x transpose: xT[i][b] = x[b][i] (512 KB, L2-resident) -------

__global__ void transpose_x(const float* __restrict__ x, float* __restrict__ xT) {
    int wid = (blockIdx.x * blockDim.x + threadIdx.x) >> 6;   // input column i
    int lane = threadIdx.x & 63;                              // batch
    if (wid >= N_IN) return;
    xT[wid * BATCH + lane] = x[lane * N_IN + wid];
}

// ---------------- layer phase A+B: gather -> group-LN -> GELU ----------------
// one wave per function node; lane = batch index.
// if-edge xe rows are virtual: value at layer l is xT[i] + l*b3[e].
// xe, h stored bf16; all math fp32.

__global__ __launch_bounds__(256) void layer_k1(
        const unsigned short* __restrict__ xe, const float* __restrict__ xT,
        const float* __restrict__ w1, const float* __restrict__ b1,
        const float* __restrict__ gamma, const float* __restrict__ beta,
        const float* __restrict__ b3, const int* __restrict__ if_off,
        const int* __restrict__ if_edges, unsigned short* __restrict__ h, int layer) {
    int wid = (blockIdx.x * blockDim.x + threadIdx.x) >> 6;
    int lane = threadIdx.x & 63;
    int f = __builtin_amdgcn_readfirstlane(wid);
    if (f >= N_FUNC) return;

    float acc[CCH];
    #pragma unroll
    for (int c = 0; c < CCH; c++) acc[c] = b1[f * CCH + c];

    if (layer > 0) {
        // ff edges: e = 16f..16f+15 (structural CSR); all 16 loads in flight
        float xv[K_FF];
        #pragma unroll
        for (int k = 0; k < K_FF; k++) xv[k] = bf2f(xe[(f * K_FF + k) * BATCH + lane]);
        #pragma unroll
        for (int k = 0; k < K_FF; k++) {
            int e = f * K_FF + k;
            #pragma unroll
            for (int c = 0; c < CCH; c++) acc[c] += xv[k] * w1[e * CCH + c];
        }
    }
    // scattered if-edges via runtime CSR; xe row virtual = xT + layer*b3
    int j0 = if_off[f], j1 = if_off[f + 1];
    float lf = (float)layer;
    for (int j = j0; j < j1; j++) {
        int e = if_edges[j];
        int ii = (e - E_FF) >> 2;
        float xv = xT[ii * BATCH + lane] + lf * b3[e];
        #pragma unroll
        for (int c = 0; c < CCH; c++) acc[c] += xv * w1[e * CCH + c];
    }

    // group-LN over the 8 channels (lane-local!) + exact GELU
    float mu = 0.f;
    #pragma unroll
    for (int c = 0; c < CCH; c++) mu += acc[c];
    mu *= 0.125f;
    float var = 0.f;
    #pragma unroll
    for (int c = 0; c < CCH; c++) { float d = acc[c] - mu; var += d * d; }
    var *= 0.125f;
    float rs = rsqrtf(var + EPS_LN);
    #pragma unroll
    for (int c = 0; c < CCH; c++) {
        float g = (acc[c] - mu) * rs * gamma[f * CCH + c] + beta[f * CCH + c];
        float ge = 0.5f * g * (1.0f + erff(g * 0.70710678118654752f));
        h[(f * CCH + c) * BATCH + lane] = f2bf(ge);
    }
}

// ---------------- layer phase C: per-src-node scatter + residual ----------------
// FIRST layer: xe rows are all zero -> pure store, no read.

template <bool FIRST>
__device__ __forceinline__ void k2_body(
        unsigned short* __restrict__ xe, const unsigned short* __restrict__ h,
        const float* __restrict__ w3, const float* __restrict__ b3,
        const int* __restrict__ src_off, const int* __restrict__ src_edges,
        int s, int lane) {
    float hreg[CCH];
    #pragma unroll
    for (int c = 0; c < CCH; c++) hreg[c] = bf2f(h[(s * CCH + c) * BATCH + lane]);
    int j0 = src_off[s], j1 = src_off[s + 1];
    int j = j0;
    for (; j + 4 <= j1; j += 4) {
        int e0 = src_edges[j], e1 = src_edges[j + 1];
        int e2 = src_edges[j + 2], e3 = src_edges[j + 3];
        float r0 = 0.f, r1 = 0.f, r2 = 0.f, r3 = 0.f;
        if (!FIRST) {
            r0 = bf2f(xe[e0 * BATCH + lane]);
            r1 = bf2f(xe[e1 * BATCH + lane]);
            r2 = bf2f(xe[e2 * BATCH + lane]);
            r3 = bf2f(xe[e3 * BATCH + lane]);
        }
        int p0 = (e0 < E_FF) ? e0 : (e0 - E_IF);
        int p1 = (e1 < E_FF) ? e1 : (e1 - E_IF);
        int p2 = (e2 < E_FF) ? e2 : (e2 - E_IF);
        int p3 = (e3 < E_FF) ? e3 : (e3 - E_IF);
        float a0 = b3[e0], a1 = b3[e1], a2 = b3[e2], a3 = b3[e3];
        #pragma unroll
        for (int c = 0; c < CCH; c++) {
            a0 += hreg[c] * w3[p0 * CCH + c];
            a1 += hreg[c] * w3[p1 * CCH + c];
            a2 += hreg[c] * w3[p2 * CCH + c];
            a3 += hreg[c] * w3[p3 * CCH + c];
        }
        xe[e0 * BATCH + lane] = f2bf(a0 + r0);
        xe[e1 * BATCH + lane] = f2bf(a1 + r1);
        xe[e2 * BATCH + lane] = f2bf(a2 + r2);
        xe[e3 * BATCH + lane] = f2bf(a3 + r3);
    }
    for (; j < j1; j++) {
        int e = src_edges[j];
        int p = (e < E_FF) ? e : (e - E_IF);
        float a = b3[e];
        if (!FIRST) a += bf2f(xe[e * BATCH + lane]);
        #pragma unroll
        for (int c = 0; c < CCH; c++) a += hreg[c] * w3[p * CCH + c];
        xe[e * BATCH + lane] = f2bf(a);
    }
}

__global__ __launch_bounds__(256) void layer_k2_first(
        unsigned short* __restrict__ xe, const unsigned short* __restrict__ h,
        const float* __restrict__ w3, const float* __restrict__ b3,
        const int* __restrict__ src_off, const int* __restrict__ src_edges) {
    int wid = (blockIdx.x * blockDim.x + threadIdx.x) >> 6;
    int lane = threadIdx.x & 63;
    int s = __builtin_amdgcn_readfirstlane(wid);
    if (s < N_FUNC) k2_body<true>(xe, h, w3, b3, src_off, src_edges, s, lane);
}

__global__ __launch_bounds__(256) void layer_k2_mid(
        unsigned short* __restrict__ xe, const unsigned short* __restrict__ h,
        const float* __restrict__ w3, const float* __restrict__ b3,
        const int* __restrict__ src_off, const int* __restrict__ src_edges) {
    int wid = (blockIdx.x * blockDim.x + threadIdx.x) >> 6;
    int lane = threadIdx.x & 63;
    int s = __builtin_amdgcn_readfirstlane(wid);
    if (s < N_FUNC) k2_body<false>(xe, h, w3, b3, src_off, src_edges, s, lane);
}

// ---------------- last layer: only the 2000 fo edges matter -> fused output ----

__global__ __launch_bounds__(256) void layer_k2_last(
        const unsigned short* __restrict__ xe, const unsigned short* __restrict__ h,
        const float* __restrict__ w3, const float* __restrict__ b3,
        const int* __restrict__ edge_src, float* __restrict__ out) {
    int wid = (blockIdx.x * blockDim.x + threadIdx.x) >> 6;   // fo index j
    int lane = threadIdx.x & 63;
    int j = __builtin_amdgcn_readfirstlane(wid);
    if (j >= N_OUT) return;
    int e = E_W1 + j;
    int s = edge_src[e];           // uniform -> s_load
    int p = e - E_IF;
    float acc = bf2f(xe[e * BATCH + lane]) + b3[e];
    float hreg[CCH];
    #pragma unroll
    for (int c = 0; c < CCH; c++) hreg[c] = bf2f(h[(s * CCH + c) * BATCH + lane]);
    #pragma unroll
    for (int c = 0; c < CCH; c++) acc += hreg[c] * w3[p * CCH + c];
    out[lane * N_OUT + j] = acc * (1.0f / N_LAYERS);
}

// ---------------- launch ----------------

extern "C" void kernel_launch(void* const* d_in, const int* in_sizes, int n_in,
                              void* d_out, int out_size, void* d_ws, size_t ws_size,
                              hipStream_t stream) {
    const float* x      = (const float*)d_in[0];
    const float* w1_val = (const float*)d_in[1];
    const float* b1     = (const float*)d_in[2];
    const float* w3_val = (const float*)d_in[3];
    const float* b3     = (const float*)d_in[4];
    const float* gamma  = (const float*)d_in[5];
    const float* beta   = (const float*)d_in[6];
    const int* edge_src = (const int*)d_in[7];
    const int* edge_dst = (const int*)d_in[8];
    float* out = (float*)d_out;

    char* base = (char*)d_ws;
    size_t off = 0;
    auto alloc = [&](size_t bytes) -> void* {
        void* p = base + off;
        off += (bytes + 255) & ~(size_t)255;
        return p;
    };
    unsigned short* xe = (unsigned short*)alloc((size_t)E_TOTAL * BATCH * 2);  // bf16, if rows unused
    unsigned short* h  = (unsigned short*)alloc((size_t)HDIM * BATCH * 2);     // bf16
    float* xT      = (float*)alloc((size_t)N_IN * BATCH * 4);
    int* if_cnt    = (int*)alloc(N_FUNC * 4);
    int* src_cnt   = (int*)alloc(N_FUNC * 4);
    int* if_offs   = (int*)alloc((N_FUNC + 1) * 4);
    int* src_offs  = (int*)alloc((N_FUNC + 1) * 4);
    int* if_cur    = (int*)alloc(N_FUNC * 4);
    int* src_cur   = (int*)alloc(N_FUNC * 4);
    int* if_edges  = (int*)alloc(E_IF * 4);
    int* src_edges = (int*)alloc((E_FF + N_OUT) * 4);
    (void)ws_size; (void)in_sizes; (void)n_in; (void)out_size;

    // CSR build (ws is re-poisoned every call, so rebuild every call)
    zero2<<<(N_FUNC + 255) / 256, 256, 0, stream>>>(if_cnt, src_cnt, N_FUNC);
    count_edges<<<(E_FF + N_OUT + 255) / 256, 256, 0, stream>>>(edge_src, edge_dst, if_cnt, src_cnt);
    scan2<<<2, 1024, 0, stream>>>(if_cnt, if_offs, if_cur, src_cnt, src_offs, src_cur);
    fill_edges<<<(E_FF + N_OUT + 255) / 256, 256, 0, stream>>>(edge_src, edge_dst,
                                                              if_cur, if_edges, src_cur, src_edges);
    transpose_x<<<(N_IN * BATCH) / 256, 256, 0, stream>>>(x, xT);

    for (int l = 0; l < N_LAYERS; l++) {
        layer_k1<<<(N_FUNC * BATCH) / 256, 256, 0, stream>>>(
            xe, xT, w1_val, b1, gamma, beta, b3, if_offs, if_edges, h, l);
        if (l == 0) {
            layer_k2_first<<<(N_FUNC * BATCH) / 256, 256, 0, stream>>>(
                xe, h, w3_val, b3, src_offs, src_edges);
        } else if (l < N_LAYERS - 1) {
            layer_k2_mid<<<(N_FUNC * BATCH) / 256, 256, 0, stream>>>(
                xe, h, w3_val, b3, src_offs, src_edges);
        } else {
            layer_k2_last<<<(N_OUT * BATCH) / 256, 256, 0, stream>>>(
                xe, h, w3_val, b3, edge_src, out);
        }
    }
}

// Round 4
// 193.963 us; speedup vs baseline: 1.6677x; 1.2422x over previous
//
#include <hip/hip_runtime.h>

#define N_FUNC 10000
#define N_IN   2000
#define N_OUT  2000
#define CCH    8
#define K_FF   16
#define E_TOTAL 170000
#define E_FF    160000   // ff edges: dst[e] = e/16 (structural), src random func
#define E_W1    168000   // ff+if edges (dst < N_FUNC)
#define E_IF    8000
#define BATCH   64
#define N_LAYERS 4
#define EPS_LN  1e-5f

#define SRC_CAP 64   // max out-degree of a func node (fixed graph, mean 16.2, max ~45)
#define IF_CAP  16   // max if-in-degree of a func node (mean 0.8)

// bf16 storage helpers: fp32 math everywhere, RNE on store.
__device__ __forceinline__ float bf2f(unsigned short u) {
    unsigned int x = ((unsigned int)u) << 16;
    return __builtin_bit_cast(float, x);
}
__device__ __forceinline__ unsigned short f2bf(float f) {
    unsigned int x = __builtin_bit_cast(unsigned int, f);
    unsigned int r = x + 0x7FFFu + ((x >> 16) & 1u);
    return (unsigned short)(r >> 16);
}

// ---------------- bucket build (no scan needed) ----------------

__global__ void zero_cnt(int* __restrict__ a, int* __restrict__ b) {
    int i = blockIdx.x * blockDim.x + threadIdx.x;
    if (i < N_FUNC) { a[i] = 0; b[i] = 0; }
}

// one pass: src out-edge buckets, if in-edge buckets, and x transpose
__global__ void fill_buckets(const int* __restrict__ src, const int* __restrict__ dst,
                             const float* __restrict__ x,
                             int* __restrict__ src_cnt, int* __restrict__ src_bkt,
                             int* __restrict__ if_cnt, int* __restrict__ if_bkt,
                             float* __restrict__ xT) {
    int i = blockIdx.x * blockDim.x + threadIdx.x;
    if (i < E_FF + N_OUT) {            // w3 edges (src is a func node)
        int e = (i < E_FF) ? i : (E_W1 + (i - E_FF));
        int s = src[e];
        int pos = atomicAdd(&src_cnt[s], 1);
        src_bkt[s * SRC_CAP + pos] = e;
    }
    if (i < E_IF) {                    // if edges, bucketed by dst
        int e = E_FF + i;
        int d = dst[e];
        int pos = atomicAdd(&if_cnt[d], 1);
        if_bkt[d * IF_CAP + pos] = e;
    }
    if (i < N_IN * BATCH) {            // xT[col][batch] = x[batch][col]
        int col = i >> 6, lane = i & 63;
        xT[col * BATCH + lane] = x[lane * N_IN + col];
    }
}

// ---------------- shared k1 body: gather -> group-LN -> GELU (h in regs) ------

__device__ __forceinline__ void compute_h(
        const unsigned short* __restrict__ xe_old, const float* __restrict__ xT,
        const float* __restrict__ w1, const float* __restrict__ b1,
        const float* __restrict__ gamma, const float* __restrict__ beta,
        const float* __restrict__ b3, const int* __restrict__ if_cnt,
        const int* __restrict__ if_bkt, int f, int lane, int layer, bool first,
        float* __restrict__ hreg) {
    float acc[CCH];
    #pragma unroll
    for (int c = 0; c < CCH; c++) acc[c] = b1[f * CCH + c];

    if (!first) {
        // ff in-edges: rows 16f..16f+15 (structural CSR); all 16 loads in flight
        float xv[K_FF];
        #pragma unroll
        for (int k = 0; k < K_FF; k++) xv[k] = bf2f(xe_old[(f * K_FF + k) * BATCH + lane]);
        #pragma unroll
        for (int k = 0; k < K_FF; k++) {
            int e = f * K_FF + k;
            #pragma unroll
            for (int c = 0; c < CCH; c++) acc[c] += xv[k] * w1[e * CCH + c];
        }
    }
    // if in-edges: virtual xe row = xT[i] + layer*b3[e] (never materialized)
    int icnt = if_cnt[f];
    float lf = (float)layer;
    for (int j = 0; j < icnt; j++) {
        int e = if_bkt[f * IF_CAP + j];
        int ii = (e - E_FF) >> 2;
        float xv = xT[ii * BATCH + lane] + lf * b3[e];
        #pragma unroll
        for (int c = 0; c < CCH; c++) acc[c] += xv * w1[e * CCH + c];
    }
    // group-LN over 8 channels (lane-local) + exact GELU
    float mu = 0.f;
    #pragma unroll
    for (int c = 0; c < CCH; c++) mu += acc[c];
    mu *= 0.125f;
    float var = 0.f;
    #pragma unroll
    for (int c = 0; c < CCH; c++) { float d = acc[c] - mu; var += d * d; }
    var *= 0.125f;
    float rs = rsqrtf(var + EPS_LN);
    #pragma unroll
    for (int c = 0; c < CCH; c++) {
        float g = (acc[c] - mu) * rs * gamma[f * CCH + c] + beta[f * CCH + c];
        hreg[c] = 0.5f * g * (1.0f + erff(g * 0.70710678118654752f));
    }
}

// ---------------- fused layer: k1 (regs) + scatter to out-edges ----------------
// one wave per func node; double-buffered xe (read old, write new).

template <bool FIRST>
__global__ __launch_bounds__(256) void layer_fused(
        const unsigned short* __restrict__ xe_old, unsigned short* __restrict__ xe_new,
        const float* __restrict__ xT, const float* __restrict__ w1,
        const float* __restrict__ b1, const float* __restrict__ gamma,
        const float* __restrict__ beta, const float* __restrict__ w3,
        const float* __restrict__ b3, const int* __restrict__ if_cnt,
        const int* __restrict__ if_bkt, const int* __restrict__ src_cnt,
        const int* __restrict__ src_bkt, int layer) {
    int wid = (blockIdx.x * blockDim.x + threadIdx.x) >> 6;
    int lane = threadIdx.x & 63;
    int f = __builtin_amdgcn_readfirstlane(wid);
    if (f >= N_FUNC) return;

    float hreg[CCH];
    compute_h(xe_old, xT, w1, b1, gamma, beta, b3, if_cnt, if_bkt,
              f, lane, layer, FIRST, hreg);

    // scatter: out-edges of f (ff + fo), residual from old buffer
    const int* bkt = src_bkt + f * SRC_CAP;
    int ocnt = src_cnt[f];
    int j = 0;
    for (; j + 4 <= ocnt; j += 4) {
        int e0 = bkt[j], e1 = bkt[j + 1], e2 = bkt[j + 2], e3 = bkt[j + 3];
        float r0 = 0.f, r1 = 0.f, r2 = 0.f, r3 = 0.f;
        if (!FIRST) {
            r0 = bf2f(xe_old[e0 * BATCH + lane]);
            r1 = bf2f(xe_old[e1 * BATCH + lane]);
            r2 = bf2f(xe_old[e2 * BATCH + lane]);
            r3 = bf2f(xe_old[e3 * BATCH + lane]);
        }
        int p0 = (e0 < E_FF) ? e0 : (e0 - E_IF);
        int p1 = (e1 < E_FF) ? e1 : (e1 - E_IF);
        int p2 = (e2 < E_FF) ? e2 : (e2 - E_IF);
        int p3 = (e3 < E_FF) ? e3 : (e3 - E_IF);
        float a0 = b3[e0], a1 = b3[e1], a2 = b3[e2], a3 = b3[e3];
        #pragma unroll
        for (int c = 0; c < CCH; c++) {
            a0 += hreg[c] * w3[p0 * CCH + c];
            a1 += hreg[c] * w3[p1 * CCH + c];
            a2 += hreg[c] * w3[p2 * CCH + c];
            a3 += hreg[c] * w3[p3 * CCH + c];
        }
        xe_new[e0 * BATCH + lane] = f2bf(a0 + r0);
        xe_new[e1 * BATCH + lane] = f2bf(a1 + r1);
        xe_new[e2 * BATCH + lane] = f2bf(a2 + r2);
        xe_new[e3 * BATCH + lane] = f2bf(a3 + r3);
    }
    for (; j < ocnt; j++) {
        int e = bkt[j];
        int p = (e < E_FF) ? e : (e - E_IF);
        float a = b3[e];
        if (!FIRST) a += bf2f(xe_old[e * BATCH + lane]);
        #pragma unroll
        for (int c = 0; c < CCH; c++) a += hreg[c] * w3[p * CCH + c];
        xe_new[e * BATCH + lane] = f2bf(a);
    }
}

// ---------------- last layer: only 2000 fo edges matter -> fused with output ----
// one wave per fo edge; recompute h[src] (<=2000 nodes vs 10000).

__global__ __launch_bounds__(256) void layer_last(
        const unsigned short* __restrict__ xe_old, const float* __restrict__ xT,
        const float* __restrict__ w1, const float* __restrict__ b1,
        const float* __restrict__ gamma, const float* __restrict__ beta,
        const float* __restrict__ w3, const float* __restrict__ b3,
        const int* __restrict__ if_cnt, const int* __restrict__ if_bkt,
        const int* __restrict__ edge_src, float* __restrict__ out) {
    int wid = (blockIdx.x * blockDim.x + threadIdx.x) >> 6;   // fo index j
    int lane = threadIdx.x & 63;
    int j = __builtin_amdgcn_readfirstlane(wid);
    if (j >= N_OUT) return;
    int e = E_W1 + j;
    int s = edge_src[e];          // uniform -> s_load

    float hreg[CCH];
    compute_h(xe_old, xT, w1, b1, gamma, beta, b3, if_cnt, if_bkt,
              s, lane, N_LAYERS - 1, false, hreg);

    int p = e - E_IF;
    float acc = bf2f(xe_old[e * BATCH + lane]) + b3[e];
    #pragma unroll
    for (int c = 0; c < CCH; c++) acc += hreg[c] * w3[p * CCH + c];
    out[lane * N_OUT + j] = acc * (1.0f / N_LAYERS);
}

// ---------------- launch ----------------

extern "C" void kernel_launch(void* const* d_in, const int* in_sizes, int n_in,
                              void* d_out, int out_size, void* d_ws, size_t ws_size,
                              hipStream_t stream) {
    const float* x      = (const float*)d_in[0];
    const float* w1_val = (const float*)d_in[1];
    const float* b1     = (const float*)d_in[2];
    const float* w3_val = (const float*)d_in[3];
    const float* b3     = (const float*)d_in[4];
    const float* gamma  = (const float*)d_in[5];
    const float* beta   = (const float*)d_in[6];
    const int* edge_src = (const int*)d_in[7];
    const int* edge_dst = (const int*)d_in[8];
    float* out = (float*)d_out;

    char* base = (char*)d_ws;
    size_t off = 0;
    auto alloc = [&](size_t bytes) -> void* {
        void* p = base + off;
        off += (bytes + 255) & ~(size_t)255;
        return p;
    };
    unsigned short* xeA = (unsigned short*)alloc((size_t)E_TOTAL * BATCH * 2);  // bf16
    unsigned short* xeB = (unsigned short*)alloc((size_t)E_TOTAL * BATCH * 2);  // bf16
    float* xT     = (float*)alloc((size_t)N_IN * BATCH * 4);
    int* src_cnt  = (int*)alloc(N_FUNC * 4);
    int* if_cnt   = (int*)alloc(N_FUNC * 4);
    int* src_bkt  = (int*)alloc((size_t)N_FUNC * SRC_CAP * 4);
    int* if_bkt   = (int*)alloc((size_t)N_FUNC * IF_CAP * 4);
    (void)ws_size; (void)in_sizes; (void)n_in; (void)out_size;

    zero_cnt<<<(N_FUNC + 255) / 256, 256, 0, stream>>>(src_cnt, if_cnt);
    fill_buckets<<<(E_FF + N_OUT + 255) / 256, 256, 0, stream>>>(
        edge_src, edge_dst, x, src_cnt, src_bkt, if_cnt, if_bkt, xT);

    // layer 0: old=xeA (virtually zero; FIRST skips all old reads), new=xeB
    layer_fused<true><<<(N_FUNC * BATCH) / 256, 256, 0, stream>>>(
        xeA, xeB, xT, w1_val, b1, gamma, beta, w3_val, b3,
        if_cnt, if_bkt, src_cnt, src_bkt, 0);
    // layer 1: B -> A
    layer_fused<false><<<(N_FUNC * BATCH) / 256, 256, 0, stream>>>(
        xeB, xeA, xT, w1_val, b1, gamma, beta, w3_val, b3,
        if_cnt, if_bkt, src_cnt, src_bkt, 1);
    // layer 2: A -> B
    layer_fused<false><<<(N_FUNC * BATCH) / 256, 256, 0, stream>>>(
        xeA, xeB, xT, w1_val, b1, gamma, beta, w3_val, b3,
        if_cnt, if_bkt, src_cnt, src_bkt, 2);
    // layer 3: read B, write only the 2000 outputs
    layer_last<<<(N_OUT * BATCH) / 256, 256, 0, stream>>>(
        xeB, xT, w1_val, b1, gamma, beta, w3_val, b3,
        if_cnt, if_bkt, edge_src, out);
}